// Round 18
// baseline (255.344 us; speedup 1.0000x reference)
//
#include <hip/hip_runtime.h>
#include <hip/hip_bf16.h>

typedef __hip_bfloat16 bf16;
typedef __attribute__((ext_vector_type(8))) short bf16x8;
typedef __attribute__((ext_vector_type(4))) float f32x4;

#define CEMB 384
#define NHEAD 6
#define HSZ 64
#define TSEQ 256
#define BATCH 128
#define MROWS (BATCH*TSEQ)   // 32768
#define FDIM 1536
#define QSCALE 0.05103103630798288f  // 384^-0.5
#define SMAX 8.0f                    // static softmax max (scores bounded ~|2.5|)

#define AS1 __attribute__((address_space(1)))
#define AS3 __attribute__((address_space(3)))
// async global->LDS, 16B/lane: LDS dest WAVE-UNIFORM base (+lane*16 by HW); global src per-lane
__device__ __forceinline__ void gload16(const void* g, void* l){
  __builtin_amdgcn_global_load_lds((const AS1 unsigned*)(g), (AS3 unsigned*)(l), 16, 0, 0);
}
__device__ __forceinline__ float b2f(unsigned short u){
  unsigned int xi = ((unsigned int)u)<<16; float f; __builtin_memcpy(&f,&xi,4); return f;
}

// ---------------- LayerNorm: fp32 in -> bf16 out (one wave per row) ----------------
__global__ __launch_bounds__(256) void ln_kernel(const float* __restrict__ x,
    const float* __restrict__ gam, const float* __restrict__ bet,
    bf16* __restrict__ y)
{
  const int row  = blockIdx.x*4 + (threadIdx.x>>6);
  const int lane = threadIdx.x & 63;
  const float* xr = x + (size_t)row*CEMB;
  float v[6]; float s = 0.f;
  #pragma unroll
  for (int i=0;i<6;i++){ v[i] = xr[lane + i*64]; s += v[i]; }
  #pragma unroll
  for (int m=1;m<64;m<<=1) s += __shfl_xor(s, m, 64);
  const float mu = s * (1.0f/CEMB);
  float qs = 0.f;
  #pragma unroll
  for (int i=0;i<6;i++){ v[i] -= mu; qs += v[i]*v[i]; }
  #pragma unroll
  for (int m=1;m<64;m<<=1) qs += __shfl_xor(qs, m, 64);
  const float rs = rsqrtf(qs*(1.0f/CEMB) + 1e-5f);
  bf16* yr = y + (size_t)row*CEMB;
  #pragma unroll
  for (int i=0;i<6;i++){
    int c = lane + i*64;
    yr[c] = __float2bfloat16(v[i]*rs*gam[c] + bet[c]);
  }
}

// ---------------- LayerNorm: bf16 in -> bf16 out (vectorized ushort2 loads) --------
__global__ __launch_bounds__(256) void ln_kernel_b(const bf16* __restrict__ x,
    const float* __restrict__ gam, const float* __restrict__ bet,
    bf16* __restrict__ y)
{
  const int row  = blockIdx.x*4 + (threadIdx.x>>6);
  const int lane = threadIdx.x & 63;
  const ushort2* xr = (const ushort2*)(x + (size_t)row*CEMB);  // 192 pairs
  float v[6]; float s = 0.f;
  #pragma unroll
  for (int i=0;i<3;i++){
    ushort2 u = xr[lane + i*64];
    v[2*i]   = b2f(u.x); v[2*i+1] = b2f(u.y);
    s += v[2*i] + v[2*i+1];
  }
  #pragma unroll
  for (int m=1;m<64;m<<=1) s += __shfl_xor(s, m, 64);
  const float mu = s * (1.0f/CEMB);
  float qs = 0.f;
  #pragma unroll
  for (int i=0;i<6;i++){ v[i] -= mu; qs += v[i]*v[i]; }
  #pragma unroll
  for (int m=1;m<64;m<<=1) qs += __shfl_xor(qs, m, 64);
  const float rs = rsqrtf(qs*(1.0f/CEMB) + 1e-5f);
  bf16* yr = y + (size_t)row*CEMB;
  #pragma unroll
  for (int i=0;i<3;i++)
    #pragma unroll
    for (int j=0;j<2;j++){
      int c = (lane + i*64)*2 + j;
      yr[c] = __float2bfloat16(v[2*i+j]*rs*gam[c] + bet[c]);
    }
}

// ---------------- Weight transpose + fp32->bf16 ----------------
__global__ __launch_bounds__(256) void transpose_to_bf16(const float* __restrict__ src,
    bf16* __restrict__ dst, int K, int N)
{
  __shared__ float tile[32][33];
  const int n0 = blockIdx.x*32, k0 = blockIdx.y*32;
  src += (size_t)blockIdx.z*K*N;
  dst += (size_t)blockIdx.z*K*N;
  const int c = threadIdx.x & 31, r8 = threadIdx.x >> 5;
  #pragma unroll
  for (int i=0;i<4;i++)
    tile[r8 + i*8][c] = src[(size_t)(k0 + r8 + i*8)*N + n0 + c];
  __syncthreads();
  #pragma unroll
  for (int i=0;i<4;i++)
    dst[(size_t)(n0 + r8 + i*8)*K + k0 + c] = __float2bfloat16(tile[c][r8 + i*8]);
}

// Merged q/k/v weight transpose: z = src_sel*6 + head; each (384,64) -> (64,384)
__global__ __launch_bounds__(256) void transpose_qkv(const float* __restrict__ Wq,
    const float* __restrict__ Wk, const float* __restrict__ Wv, bf16* __restrict__ dst)
{
  __shared__ float tile[32][33];
  const int z = blockIdx.z;
  const float* src = (z < 6) ? Wq : (z < 12 ? Wk : Wv);
  src += (size_t)(z % 6) * CEMB * HSZ;
  dst += (size_t)z * CEMB * HSZ;
  const int n0 = blockIdx.x*32, k0 = blockIdx.y*32;
  const int c = threadIdx.x & 31, r8 = threadIdx.x >> 5;
  #pragma unroll
  for (int i=0;i<4;i++)
    tile[r8 + i*8][c] = src[(size_t)(k0 + r8 + i*8)*HSZ + n0 + c];
  __syncthreads();
  #pragma unroll
  for (int i=0;i<4;i++)
    dst[(size_t)(n0 + r8 + i*8)*CEMB + k0 + c] = __float2bfloat16(tile[c][r8 + i*8]);
}

// ====== gemm8e — 4-phase k-half-staggered GEMM (gemm8n structure; A/B MEASURED
// MfmaUtil 31-37% vs 25% for ALL 2-phase variants, R14/R16/R17) ======================
// C[M, NT*192] = A[M,384] @ BT[N,384]^T. BM=256, BN=192, BK=64, NK=6, 8 waves
// (2M x 4N, wave 128x48, acc[8][3], 12 MFMA/phase). grid = 128*NT (%8==0: NT in 2,6,8).
// LDS 112KB: A 2 slots x {k-half 16KB}x2 @0; B 2 slots x 24KB [192r][128B] @65536.
// Per K-tile: ph1(mh0,k0) rdA+rdB, stgA-k0(kt+1); ph2(mh1,k0) rdA (bq reuse),
// stgB(kt+1), vmcnt(5); ph3(mh0,k1) rdA+rdB, stgA-k1(kt+1); ph4(mh1,k1) rdA, vmcnt(2).
// Each phase: barrier; lgkmcnt(0)+sched_barrier; setprio(1) 12 MFMA setprio(0); barrier.
// Ledger (R16-verified): vmcnt never 0 mid-loop; slot WAR separated by phase barriers.
// EPI: 0 = QKV scatter (q scaled; sel block-uniform since 192|384), 1 = +bias+
//      resid(f32) -> bf16, 2 = relu(+bias) -> bf16
template<int EPI, int NT>
__global__ __launch_bounds__(512, 2) void gemm8e(
    const bf16* __restrict__ A, const bf16* __restrict__ BT,
    const float* __restrict__ bias, const float* __restrict__ residf,
    bf16* __restrict__ outb0, bf16* __restrict__ outb1, bf16* __restrict__ outb2)
{
  constexpr int K = 384, NK = 6;
  constexpr int N = NT*192;
  __shared__ char lds[114688];        // A: 2x32KB @0; B: 2x24KB @65536
  const int cpx = gridDim.x >> 3;
  const int wg  = (blockIdx.x & 7)*cpx + (blockIdx.x >> 3);
  const int bm = (wg / NT)*256, bn = (wg % NT)*192;
  const int t = threadIdx.x, lane = t & 63, wid = t >> 6;
  const int wm = wid >> 2, wn = wid & 3;
  const int g = lane >> 4, fr = lane & 15;
  const size_t rowb = (size_t)K*2;
  const int sblkA = ((t&3) ^ ((t>>3)&3)) << 4;
  const int swzA  = (g ^ ((fr>>1)&3)) << 4;
  f32x4 acc[8][3] = {};

  const char* Ag = (const char*)A + (size_t)(bm + (t>>2))*rowb + sblkA;
  const size_t rstep = rowb*128;

  auto stgA = [&](int KH, int sl, int kt2){
    const char* src = Ag + (size_t)kt2*128 + KH*64;
    char* dst = lds + sl*32768 + KH*16384 + wid*1024;
    gload16(src,         dst);
    gload16(src + rstep, dst + 8192);
  };
  auto stgB = [&](int sl, int kt2){
    #pragma unroll
    for (int j=0;j<3;j++){
      int slot = t + j*512;
      int row = slot>>3, blk = slot&7;
      gload16((const char*)BT + (size_t)(bn + row)*rowb + (size_t)kt2*128 + ((blk ^ (row&7))<<4),
              lds + 65536 + sl*24576 + j*8192 + wid*1024);
    }
  };
  auto rdA = [&](bf16x8* af, int sl, int MH, int KS){
    const char* p = lds + sl*32768 + KS*16384 + (wm*128 + MH*64 + fr)*64 + swzA;
    #pragma unroll
    for (int mi=0;mi<4;mi++) af[mi] = *(const bf16x8*)(p + mi*1024);
  };
  auto rdB = [&](bf16x8* bq, int sl, int ks){
    #pragma unroll
    for (int nj=0;nj<3;nj++){
      int row = wn*48 + nj*16 + fr;
      bq[nj] = *(const bf16x8*)(lds + 65536 + sl*24576 + row*128 + (((ks*4+g) ^ (row&7))<<4));
    }
  };

#define MFMA12(MH) \
  __builtin_amdgcn_s_setprio(1); \
  _Pragma("unroll") \
  for (int mi=0;mi<4;mi++){ \
    _Pragma("unroll") \
    for (int nj=0;nj<3;nj++) \
      acc[(MH)*4+mi][nj] = __builtin_amdgcn_mfma_f32_16x16x32_bf16(af[mi], bq[nj], acc[(MH)*4+mi][nj], 0, 0, 0); \
  } \
  __builtin_amdgcn_s_setprio(0);

  stgA(0,0,0); stgB(0,0); stgA(1,0,0);
  asm volatile("s_waitcnt vmcnt(2)" ::: "memory");   // A-k0 + B landed
  __builtin_amdgcn_s_barrier();

  #pragma unroll 1
  for (int kt=0; kt<NK; ++kt){
    const int sl = kt&1, sn = sl^1;
    const bool pf = (kt+1 < NK);
    bf16x8 af[4], bq[3];
    rdA(af, sl, 0, 0); rdB(bq, sl, 0);
    if (pf) stgA(0,sn,kt+1);
    __builtin_amdgcn_s_barrier();
    asm volatile("s_waitcnt lgkmcnt(0)" ::: "memory");
    __builtin_amdgcn_sched_barrier(0);
    MFMA12(0)
    __builtin_amdgcn_s_barrier();
    rdA(af, sl, 1, 0);
    if (pf){ stgB(sn,kt+1);
             asm volatile("s_waitcnt vmcnt(5)" ::: "memory"); }
    else     asm volatile("s_waitcnt vmcnt(0)" ::: "memory");
    __builtin_amdgcn_s_barrier();
    asm volatile("s_waitcnt lgkmcnt(0)" ::: "memory");
    __builtin_amdgcn_sched_barrier(0);
    MFMA12(1)
    __builtin_amdgcn_s_barrier();
    rdA(af, sl, 0, 1); rdB(bq, sl, 1);
    if (pf) stgA(1,sn,kt+1);
    __builtin_amdgcn_s_barrier();
    asm volatile("s_waitcnt lgkmcnt(0)" ::: "memory");
    __builtin_amdgcn_sched_barrier(0);
    MFMA12(0)
    __builtin_amdgcn_s_barrier();
    rdA(af, sl, 1, 1);
    if (pf) asm volatile("s_waitcnt vmcnt(2)" ::: "memory");
    __builtin_amdgcn_s_barrier();
    asm volatile("s_waitcnt lgkmcnt(0)" ::: "memory");
    __builtin_amdgcn_sched_barrier(0);
    MFMA12(1)
    __builtin_amdgcn_s_barrier();
  }
#undef MFMA12

  // epilogue: m = bm + wm*128 + mi*16 + 4g + e; n = bn + wn*48 + nj*16 + fr
  if constexpr (EPI==0){
    const int sel = bn/CEMB;            // block-uniform: 192-col block within one sel
    bf16* dst = sel==0 ? outb0 : (sel==1 ? outb1 : outb2);
    const float sc = sel==0 ? QSCALE : 1.0f;
    const int nb = bn - sel*CEMB;
    #pragma unroll
    for (int nj=0;nj<3;nj++){
      const int nn = nb + wn*48 + nj*16 + fr;
      const int hh = nn>>6, dd = nn&63;
      #pragma unroll
      for (int mi=0;mi<8;mi++){
        const int m0 = bm + wm*128 + mi*16 + 4*g;
        const int bb = m0>>8, tt0 = m0&255;
        bf16* p = dst + ((size_t)(bb*NHEAD + hh)*TSEQ + tt0)*HSZ + dd;
        #pragma unroll
        for (int e=0;e<4;e++)
          p[(size_t)e*HSZ] = __float2bfloat16(acc[mi][nj][e]*sc);
      }
    }
  } else {
    #pragma unroll
    for (int mi=0;mi<8;mi++)
      #pragma unroll
      for (int nj=0;nj<3;nj++)
        #pragma unroll
        for (int e=0;e<4;e++){
          const int m = bm + wm*128 + mi*16 + 4*g + e;
          const int n = bn + wn*48 + nj*16 + fr;
          const float vacc = acc[mi][nj][e];
          if constexpr (EPI==1){
            outb0[(size_t)m*N + n] = __float2bfloat16(vacc + bias[n] + residf[(size_t)m*N + n]);
          } else {
            float z = vacc + bias[n];
            outb0[(size_t)m*N + n] = __float2bfloat16(z > 0.f ? z : 0.f);
          }
        }
  }
}

// ====== gemm8n — FF2: 4-phase k-half-staggered schedule, BN=192 (R16-verified) =======
template<int NK>
__global__ __launch_bounds__(512, 2) void gemm8n(
    const bf16* __restrict__ A, const bf16* __restrict__ BT,
    const float* __restrict__ bias, const bf16* __restrict__ residb,
    float* __restrict__ outf)
{
  constexpr int K = NK*64;
  __shared__ char lds[114688];        // A: 2x32KB @0; B: 2x24KB @65536
  const int cpx = gridDim.x >> 3;
  const int wg  = (blockIdx.x & 7)*cpx + (blockIdx.x >> 3);
  const int bm = (wg >> 1)*256, bn = (wg & 1)*192;
  const int t = threadIdx.x, lane = t & 63, wid = t >> 6;
  const int wm = wid >> 2, wn = wid & 3;
  const int g = lane >> 4, fr = lane & 15;
  const size_t rowb = (size_t)K*2;
  const int sblkA = ((t&3) ^ ((t>>3)&3)) << 4;
  const int swzA  = (g ^ ((fr>>1)&3)) << 4;
  f32x4 acc[8][3] = {};

  const char* Ag = (const char*)A + (size_t)(bm + (t>>2))*rowb + sblkA;
  const size_t rstep = rowb*128;

  auto stgA = [&](int KH, int sl, int kt2){
    const char* src = Ag + (size_t)kt2*128 + KH*64;
    char* dst = lds + sl*32768 + KH*16384 + wid*1024;
    gload16(src,         dst);
    gload16(src + rstep, dst + 8192);
  };
  auto stgB = [&](int sl, int kt2){
    #pragma unroll
    for (int j=0;j<3;j++){
      int slot = t + j*512;
      int row = slot>>3, blk = slot&7;
      gload16((const char*)BT + (size_t)(bn + row)*rowb + (size_t)kt2*128 + ((blk ^ (row&7))<<4),
              lds + 65536 + sl*24576 + j*8192 + wid*1024);
    }
  };
  auto rdA = [&](bf16x8* af, int sl, int MH, int KS){
    const char* p = lds + sl*32768 + KS*16384 + (wm*128 + MH*64 + fr)*64 + swzA;
    #pragma unroll
    for (int mi=0;mi<4;mi++) af[mi] = *(const bf16x8*)(p + mi*1024);
  };
  auto rdB = [&](bf16x8* bq, int sl, int ks){
    #pragma unroll
    for (int nj=0;nj<3;nj++){
      int row = wn*48 + nj*16 + fr;
      bq[nj] = *(const bf16x8*)(lds + 65536 + sl*24576 + row*128 + (((ks*4+g) ^ (row&7))<<4));
    }
  };

#define MFMA12(MH) \
  __builtin_amdgcn_s_setprio(1); \
  _Pragma("unroll") \
  for (int mi=0;mi<4;mi++){ \
    _Pragma("unroll") \
    for (int nj=0;nj<3;nj++) \
      acc[(MH)*4+mi][nj] = __builtin_amdgcn_mfma_f32_16x16x32_bf16(af[mi], bq[nj], acc[(MH)*4+mi][nj], 0, 0, 0); \
  } \
  __builtin_amdgcn_s_setprio(0);

  stgA(0,0,0); stgB(0,0); stgA(1,0,0);
  asm volatile("s_waitcnt vmcnt(2)" ::: "memory");
  __builtin_amdgcn_s_barrier();

  #pragma unroll 1
  for (int kt=0; kt<NK; ++kt){
    const int sl = kt&1, sn = sl^1;
    const bool pf = (kt+1 < NK);
    bf16x8 af[4], bq[3];
    rdA(af, sl, 0, 0); rdB(bq, sl, 0);
    if (pf) stgA(0,sn,kt+1);
    __builtin_amdgcn_s_barrier();
    asm volatile("s_waitcnt lgkmcnt(0)" ::: "memory");
    __builtin_amdgcn_sched_barrier(0);
    MFMA12(0)
    __builtin_amdgcn_s_barrier();
    rdA(af, sl, 1, 0);
    if (pf){ stgB(sn,kt+1);
             asm volatile("s_waitcnt vmcnt(5)" ::: "memory"); }
    else     asm volatile("s_waitcnt vmcnt(0)" ::: "memory");
    __builtin_amdgcn_s_barrier();
    asm volatile("s_waitcnt lgkmcnt(0)" ::: "memory");
    __builtin_amdgcn_sched_barrier(0);
    MFMA12(1)
    __builtin_amdgcn_s_barrier();
    rdA(af, sl, 0, 1); rdB(bq, sl, 1);
    if (pf) stgA(1,sn,kt+1);
    __builtin_amdgcn_s_barrier();
    asm volatile("s_waitcnt lgkmcnt(0)" ::: "memory");
    __builtin_amdgcn_sched_barrier(0);
    MFMA12(0)
    __builtin_amdgcn_s_barrier();
    rdA(af, sl, 1, 1);
    if (pf) asm volatile("s_waitcnt vmcnt(2)" ::: "memory");
    __builtin_amdgcn_s_barrier();
    asm volatile("s_waitcnt lgkmcnt(0)" ::: "memory");
    __builtin_amdgcn_sched_barrier(0);
    MFMA12(1)
    __builtin_amdgcn_s_barrier();
  }
#undef MFMA12

  #pragma unroll
  for (int mi=0;mi<8;mi++)
    #pragma unroll
    for (int nj=0;nj<3;nj++)
      #pragma unroll
      for (int e=0;e<4;e++){
        const int m = bm + wm*128 + mi*16 + 4*g + e;
        const int n = bn + wn*48 + nj*16 + fr;
        outf[(size_t)m*CEMB + n] = acc[mi][nj][e] + bias[n] +
            b2f(*(const unsigned short*)&residb[(size_t)m*CEMB + n]);
      }
}

// ---------------- Causal flash attention, one block per (b,h), 4 waves x 64 rows ----
__global__ __launch_bounds__(256) void attn_kernel(
    const bf16* __restrict__ q, const bf16* __restrict__ k,
    const bf16* __restrict__ v, bf16* __restrict__ out)
{
  __shared__ char kt_lds[64*128];
  __shared__ char vt_lds[80*128];
  __shared__ char p_lds[4][64*128];
  const int bh = blockIdx.x;
  const int bidx = bh / NHEAD, hidx = bh - bidx*NHEAD;
  const int t = threadIdx.x, lane = t & 63, w = t >> 6;
  const int g = lane >> 4, fr = lane & 15;
  const int lrow = lane >> 3;
  const int scol = ((lane & 7) ^ lrow) << 4;
  const size_t base = (size_t)bh * TSEQ * HSZ;

  if (t < 128){
    unsigned int ones2 = 0x3F803F80u;
    uint4 vv;
    if ((t>>3) == 0) vv = uint4{ones2, ones2, ones2, ones2};
    else             vv = uint4{0u, 0u, 0u, 0u};
    *(uint4*)(vt_lds + (64 + (t>>3))*128 + (t&7)*16) = vv;
  }

  bf16x8 qf[4][2];
  #pragma unroll
  for (int mi=0;mi<4;mi++)
    #pragma unroll
    for (int ks=0;ks<2;ks++)
      qf[mi][ks] = *(const bf16x8*)(q + base + (size_t)(w*64 + mi*16 + fr)*HSZ + ks*32 + g*8);

  f32x4 of[4][5] = {};

  for (int j=0;j<4;j++){
    __syncthreads();
    #pragma unroll
    for (int i=0;i<2;i++){
      int r0 = w*16 + i*8;
      gload16((const char*)(k + base + (size_t)(j*64 + r0 + lrow)*HSZ) + scol,
              kt_lds + r0*128);
    }
    #pragma unroll
    for (int i=0;i<2;i++){
      int chunk = t + i*256, r = chunk>>3, c = chunk&7;
      uint4 vv = *(const uint4*)(v + base + (size_t)(j*64 + r)*HSZ + c*8);
      const unsigned short* pv = (const unsigned short*)&vv;
      #pragma unroll
      for (int u=0;u<8;u++)
        *(unsigned short*)(vt_lds + (c*8+u)*128 + ((((r>>3) ^ u ^ c)&7)<<4) + (r&7)*2) = pv[u];
    }
    __syncthreads();
    if (j <= w){
      f32x4 sa[4][4] = {};
      #pragma unroll
      for (int ks=0;ks<2;ks++){
        bf16x8 kf[4];
        #pragma unroll
        for (int nj=0;nj<4;nj++)
          kf[nj] = *(const bf16x8*)(kt_lds + (nj*16+fr)*128 + (((ks*4+g)*16) ^ ((fr&7)<<4)));
        __builtin_amdgcn_s_setprio(1);
        #pragma unroll
        for (int mi=0;mi<4;mi++)
          #pragma unroll
          for (int nj=0;nj<4;nj++)
            sa[mi][nj] = __builtin_amdgcn_mfma_f32_16x16x32_bf16(qf[mi][ks], kf[nj], sa[mi][nj], 0, 0, 0);
        __builtin_amdgcn_s_setprio(0);
      }
      if (j == w){
        #pragma unroll
        for (int mi=0;mi<4;mi++)
          #pragma unroll
          for (int nj=0;nj<4;nj++)
            #pragma unroll
            for (int e=0;e<4;e++)
              if (nj*16 + fr > mi*16 + 4*g + e) sa[mi][nj][e] = -1e30f;
      }
      char* pl = p_lds[w];
      #pragma unroll
      for (int mi=0;mi<4;mi++)
        #pragma unroll
        for (int nj=0;nj<4;nj++)
          #pragma unroll
          for (int e=0;e<4;e++){
            int row = mi*16 + 4*g + e, col = nj*16 + fr;
            float p = __expf(sa[mi][nj][e] - SMAX);
            *(bf16*)(pl + row*128 + (((col>>3) ^ (row&7))<<4) + (col&7)*2) =
                __float2bfloat16(p);
          }
      #pragma unroll
      for (int ks=0;ks<2;ks++){
        bf16x8 pa[4], vf[5];
        #pragma unroll
        for (int mi=0;mi<4;mi++)
          pa[mi] = *(const bf16x8*)(pl + (mi*16+fr)*128 + (((ks*4+g)*16) ^ ((fr&7)<<4)));
        #pragma unroll
        for (int nd=0;nd<5;nd++){
          int d = nd*16 + fr;
          vf[nd] = *(const bf16x8*)(vt_lds + d*128 +
                   ((((ks*4+g) ^ (d&7) ^ ((d>>3)&7))&7)<<4));
        }
        __builtin_amdgcn_s_setprio(1);
        #pragma unroll
        for (int mi=0;mi<4;mi++)
          #pragma unroll
          for (int nd=0;nd<5;nd++)
            of[mi][nd] = __builtin_amdgcn_mfma_f32_16x16x32_bf16(pa[mi], vf[nd], of[mi][nd], 0, 0, 0);
        __builtin_amdgcn_s_setprio(0);
      }
    }
  }
  #pragma unroll
  for (int mi=0;mi<4;mi++){
    float rl[4];
    #pragma unroll
    for (int e=0;e<4;e++){
      float l = __shfl(of[mi][4][e], (int)(lane & 48), 64);
      rl[e] = 1.0f / l;
    }
    #pragma unroll
    for (int nd=0;nd<4;nd++)
      #pragma unroll
      for (int e=0;e<4;e++){
        int row = w*64 + mi*16 + 4*g + e;
        int d = nd*16 + fr;
        out[(size_t)(bidx*TSEQ + row)*CEMB + hidx*HSZ + d] =
            __float2bfloat16(of[mi][nd][e] * rl[e]);
      }
  }
}

// ---------------- launch ----------------
extern "C" void kernel_launch(void* const* d_in, const int* in_sizes, int n_in,
                              void* d_out, int out_size, void* d_ws, size_t ws_size,
                              hipStream_t stream)
{
  const float* x     = (const float*)d_in[0];
  const float* Wq    = (const float*)d_in[1];
  const float* Wk    = (const float*)d_in[2];
  const float* Wv    = (const float*)d_in[3];
  const float* Wproj = (const float*)d_in[4];
  const float* bproj = (const float*)d_in[5];
  const float* W1    = (const float*)d_in[6];
  const float* b1    = (const float*)d_in[7];
  const float* W2    = (const float*)d_in[8];
  const float* b2    = (const float*)d_in[9];
  const float* ln1g  = (const float*)d_in[10];
  const float* ln1b  = (const float*)d_in[11];
  const float* ln2g  = (const float*)d_in[12];
  const float* ln2b  = (const float*)d_in[13];

  char* ws = (char*)d_ws;
  const size_t SA = (size_t)MROWS*CEMB*2;          // one bf16 M x C slot
  bf16* xn1    = (bf16*)(ws + 0*SA);               // LN1 out      (slot 0)
  bf16* qb     = (bf16*)(ws + 1*SA);               // q (b,h,t,d), pre-scaled
  bf16* kbuf   = (bf16*)(ws + 2*SA);               // k (b,h,t,d)
  bf16* vb     = (bf16*)(ws + 3*SA);               // v (b,h,t,d)
  bf16* attn_o = (bf16*)(ws + 0*SA);               // reuse slot 0 (xn1 dead after QKV)
  bf16* act    = (bf16*)(ws + 0*SA);               // FF1 out, slots 0-3
  bf16* hb     = (bf16*)(ws + 4*SA);               // LN2 out
  bf16* x1b    = (bf16*)(ws + 5*SA);               // residual stream after attn (bf16)
  char* wb     = ws + 5*SA + (size_t)MROWS*CEMB*4;
  bf16* qkvT   = (bf16*)wb;                                   // (1152, 384)
  bf16* projT  = (bf16*)(wb + (size_t)1152*384*2);            // (384, 384)
  bf16* w1T    = (bf16*)(wb + (size_t)(1152+384)*384*2);      // (1536, 384)
  bf16* w2T    = (bf16*)(wb + (size_t)(1152+384+1536)*384*2); // (384, 1536)

  dim3 blk(256), blk5(512);
  transpose_qkv<<<dim3(2,12,18), blk, 0, stream>>>(Wq, Wk, Wv, qkvT);
  transpose_to_bf16<<<dim3(12,12,1), blk, 0, stream>>>(Wproj, projT, CEMB, CEMB);
  transpose_to_bf16<<<dim3(48,12,1), blk, 0, stream>>>(W1,    w1T,   CEMB, FDIM);
  transpose_to_bf16<<<dim3(12,48,1), blk, 0, stream>>>(W2,    w2T,   FDIM, CEMB);

  ln_kernel<<<dim3(MROWS/4), blk, 0, stream>>>(x, ln1g, ln1b, xn1);
  gemm8e<0,6><<<dim3(768), blk5, 0, stream>>>(xn1, qkvT, nullptr, nullptr,
                                              qb, kbuf, vb);
  attn_kernel<<<dim3(768), blk, 0, stream>>>(qb, kbuf, vb, attn_o);
  gemm8e<1,2><<<dim3(256), blk5, 0, stream>>>(attn_o, projT, bproj, x,
                                              x1b, nullptr, nullptr);
  ln_kernel_b<<<dim3(MROWS/4), blk, 0, stream>>>(x1b, ln2g, ln2b, hb);
  gemm8e<2,8><<<dim3(1024), blk5, 0, stream>>>(hb, w1T, b1, nullptr,
                                               act, nullptr, nullptr);
  gemm8n<24><<<dim3(256), blk5, 0, stream>>>(act, w2T, b2, x1b, (float*)d_out);
}

// Round 19
// 236.666 us; speedup vs baseline: 1.0789x; 1.0789x over previous
//
#include <hip/hip_runtime.h>
#include <hip/hip_bf16.h>

typedef __hip_bfloat16 bf16;
typedef __attribute__((ext_vector_type(8))) short bf16x8;
typedef __attribute__((ext_vector_type(4))) float f32x4;

#define CEMB 384
#define NHEAD 6
#define HSZ 64
#define TSEQ 256
#define BATCH 128
#define MROWS (BATCH*TSEQ)   // 32768
#define FDIM 1536
#define QSCALE 0.05103103630798288f  // 384^-0.5
#define SMAX 8.0f                    // static softmax max (scores bounded ~|2.5|)

#define AS1 __attribute__((address_space(1)))
#define AS3 __attribute__((address_space(3)))
// async global->LDS, 16B/lane: LDS dest WAVE-UNIFORM base (+lane*16 by HW); global src per-lane
__device__ __forceinline__ void gload16(const void* g, void* l){
  __builtin_amdgcn_global_load_lds((const AS1 unsigned*)(g), (AS3 unsigned*)(l), 16, 0, 0);
}
__device__ __forceinline__ float b2f(unsigned short u){
  unsigned int xi = ((unsigned int)u)<<16; float f; __builtin_memcpy(&f,&xi,4); return f;
}

// ---------------- LayerNorm: fp32 in -> bf16 out (one wave per row) ----------------
__global__ __launch_bounds__(256) void ln_kernel(const float* __restrict__ x,
    const float* __restrict__ gam, const float* __restrict__ bet,
    bf16* __restrict__ y)
{
  const int row  = blockIdx.x*4 + (threadIdx.x>>6);
  const int lane = threadIdx.x & 63;
  const float* xr = x + (size_t)row*CEMB;
  float v[6]; float s = 0.f;
  #pragma unroll
  for (int i=0;i<6;i++){ v[i] = xr[lane + i*64]; s += v[i]; }
  #pragma unroll
  for (int m=1;m<64;m<<=1) s += __shfl_xor(s, m, 64);
  const float mu = s * (1.0f/CEMB);
  float qs = 0.f;
  #pragma unroll
  for (int i=0;i<6;i++){ v[i] -= mu; qs += v[i]*v[i]; }
  #pragma unroll
  for (int m=1;m<64;m<<=1) qs += __shfl_xor(qs, m, 64);
  const float rs = rsqrtf(qs*(1.0f/CEMB) + 1e-5f);
  bf16* yr = y + (size_t)row*CEMB;
  #pragma unroll
  for (int i=0;i<6;i++){
    int c = lane + i*64;
    yr[c] = __float2bfloat16(v[i]*rs*gam[c] + bet[c]);
  }
}

// ---------------- LayerNorm: bf16 in -> bf16 out (vectorized ushort2 loads) --------
__global__ __launch_bounds__(256) void ln_kernel_b(const bf16* __restrict__ x,
    const float* __restrict__ gam, const float* __restrict__ bet,
    bf16* __restrict__ y)
{
  const int row  = blockIdx.x*4 + (threadIdx.x>>6);
  const int lane = threadIdx.x & 63;
  const ushort2* xr = (const ushort2*)(x + (size_t)row*CEMB);  // 192 pairs
  float v[6]; float s = 0.f;
  #pragma unroll
  for (int i=0;i<3;i++){
    ushort2 u = xr[lane + i*64];
    v[2*i]   = b2f(u.x); v[2*i+1] = b2f(u.y);
    s += v[2*i] + v[2*i+1];
  }
  #pragma unroll
  for (int m=1;m<64;m<<=1) s += __shfl_xor(s, m, 64);
  const float mu = s * (1.0f/CEMB);
  float qs = 0.f;
  #pragma unroll
  for (int i=0;i<6;i++){ v[i] -= mu; qs += v[i]*v[i]; }
  #pragma unroll
  for (int m=1;m<64;m<<=1) qs += __shfl_xor(qs, m, 64);
  const float rs = rsqrtf(qs*(1.0f/CEMB) + 1e-5f);
  bf16* yr = y + (size_t)row*CEMB;
  #pragma unroll
  for (int i=0;i<3;i++)
    #pragma unroll
    for (int j=0;j<2;j++){
      int c = (lane + i*64)*2 + j;
      yr[c] = __float2bfloat16(v[2*i+j]*rs*gam[c] + bet[c]);
    }
}

// ---------------- Weight transpose + fp32->bf16 ----------------
__global__ __launch_bounds__(256) void transpose_to_bf16(const float* __restrict__ src,
    bf16* __restrict__ dst, int K, int N)
{
  __shared__ float tile[32][33];
  const int n0 = blockIdx.x*32, k0 = blockIdx.y*32;
  src += (size_t)blockIdx.z*K*N;
  dst += (size_t)blockIdx.z*K*N;
  const int c = threadIdx.x & 31, r8 = threadIdx.x >> 5;
  #pragma unroll
  for (int i=0;i<4;i++)
    tile[r8 + i*8][c] = src[(size_t)(k0 + r8 + i*8)*N + n0 + c];
  __syncthreads();
  #pragma unroll
  for (int i=0;i<4;i++)
    dst[(size_t)(n0 + r8 + i*8)*K + k0 + c] = __float2bfloat16(tile[c][r8 + i*8]);
}

// Merged q/k/v weight transpose: z = src_sel*6 + head; each (384,64) -> (64,384)
__global__ __launch_bounds__(256) void transpose_qkv(const float* __restrict__ Wq,
    const float* __restrict__ Wk, const float* __restrict__ Wv, bf16* __restrict__ dst)
{
  __shared__ float tile[32][33];
  const int z = blockIdx.z;
  const float* src = (z < 6) ? Wq : (z < 12 ? Wk : Wv);
  src += (size_t)(z % 6) * CEMB * HSZ;
  dst += (size_t)z * CEMB * HSZ;
  const int n0 = blockIdx.x*32, k0 = blockIdx.y*32;
  const int c = threadIdx.x & 31, r8 = threadIdx.x >> 5;
  #pragma unroll
  for (int i=0;i<4;i++)
    tile[r8 + i*8][c] = src[(size_t)(k0 + r8 + i*8)*HSZ + n0 + c];
  __syncthreads();
  #pragma unroll
  for (int i=0;i<4;i++)
    dst[(size_t)(n0 + r8 + i*8)*CEMB + k0 + c] = __float2bfloat16(tile[c][r8 + i*8]);
}

// ====== gemm5 — 3-slot 2-iteration-cover GEMM (R17 best config) =====================
// BM=256, BN=128, BK=32, 8 waves (512 thr, 4M x 2N, wave tile 64x64), 16x16x32 MFMA.
// LDS = 3 slots x (A 16KB + B 8KB) = 72KB -> 2 blocks/CU.
// Swizzle (R5, MEASURED 0 conflicts). XCD swizzle (T1, bijective, nwg%8==0).
// EPI: 0 = QKV scatter (q scaled), 1 = +bias+resid(f32) -> BF16 x1, 2 = relu(+bias)->bf16
template<int EPI, int NN, int NK>
__global__ __launch_bounds__(512) void gemm5(
    const bf16* __restrict__ A, const bf16* __restrict__ BT,
    const float* __restrict__ bias, const float* __restrict__ resid,
    float* __restrict__ outf, bf16* __restrict__ outb0,
    bf16* __restrict__ outb1, bf16* __restrict__ outb2)
{
  constexpr int K = NK*32;
  constexpr int N = NN*128;
  __shared__ char lA[3][256*64];
  __shared__ char lB[3][128*64];
  const int cpx = gridDim.x >> 3;
  const int wg  = (blockIdx.x & 7)*cpx + (blockIdx.x >> 3);
  const int bm = (wg / NN)*256, bn = (wg % NN)*128;
  const int t = threadIdx.x, lane = t & 63, wid = t >> 6;
  const int wr = (wid>>1)*64, wc = (wid&1)*64;
  const int g = lane >> 4, fr = lane & 15;
  const size_t rowK2 = (size_t)K*2;
  f32x4 acc[4][4] = {};

  auto stage = [&](int sl, int kt){
    const size_t ko = (size_t)kt*64;
    #pragma unroll
    for (int i=0;i<2;i++){
      int slot = t + i*512;
      int row = slot>>2, blk = slot&3;
      gload16((const char*)A + (size_t)(bm+row)*rowK2 + ko + ((blk ^ ((row>>1)&3))<<4),
              lA[sl] + slot*16);
    }
    {
      int row = t>>2, blk = t&3;
      gload16((const char*)BT + (size_t)(bn+row)*rowK2 + ko + ((blk ^ ((row>>1)&3))<<4),
              lB[sl] + t*16);
    }
  };

  stage(0,0); stage(1,1); stage(2,2);
  #pragma unroll 1
  for (int kt=0; kt<NK; ++kt){
    const int rem = NK-1-kt;
    if (rem >= 2)      asm volatile("s_waitcnt vmcnt(6)" ::: "memory");
    else if (rem == 1) asm volatile("s_waitcnt vmcnt(3)" ::: "memory");
    else               asm volatile("s_waitcnt vmcnt(0)" ::: "memory");
    __builtin_amdgcn_s_barrier();
    const int cur = kt%3;
    bf16x8 af[4], bq[4];
    #pragma unroll
    for (int mi=0;mi<4;mi++){
      int row = wr + mi*16 + fr;
      af[mi] = *(const bf16x8*)(lA[cur] + row*64 + ((g ^ ((row>>1)&3))<<4));
    }
    #pragma unroll
    for (int nj=0;nj<4;nj++){
      int row = wc + nj*16 + fr;
      bq[nj] = *(const bf16x8*)(lB[cur] + row*64 + ((g ^ ((row>>1)&3))<<4));
    }
    asm volatile("s_waitcnt lgkmcnt(0)" ::: "memory");
    __builtin_amdgcn_sched_barrier(0);
    __builtin_amdgcn_s_barrier();
    if (kt+3 < NK) stage(cur, kt+3);
    __builtin_amdgcn_s_setprio(1);
    #pragma unroll
    for (int mi=0;mi<4;mi++)
      #pragma unroll
      for (int nj=0;nj<4;nj++)
        acc[mi][nj] = __builtin_amdgcn_mfma_f32_16x16x32_bf16(af[mi], bq[nj], acc[mi][nj], 0, 0, 0);
    __builtin_amdgcn_s_setprio(0);
  }

  if constexpr (EPI==0){
    const int sel = bn/CEMB;
    bf16* dst = sel==0 ? outb0 : (sel==1 ? outb1 : outb2);
    const float sc = sel==0 ? QSCALE : 1.0f;
    const int nb = bn - sel*CEMB;
    #pragma unroll
    for (int nj=0;nj<4;nj++){
      const int nn = nb + wc + nj*16 + fr;
      const int hh = nn>>6, dd = nn&63;
      #pragma unroll
      for (int mi=0;mi<4;mi++){
        const int m0 = bm + wr + mi*16 + 4*g;
        const int bb = m0>>8, tt0 = m0&255;
        bf16* p = dst + ((size_t)(bb*NHEAD + hh)*TSEQ + tt0)*HSZ + dd;
        #pragma unroll
        for (int e=0;e<4;e++)
          p[(size_t)e*HSZ] = __float2bfloat16(acc[mi][nj][e]*sc);
      }
    }
  } else {
    #pragma unroll
    for (int mi=0;mi<4;mi++)
      #pragma unroll
      for (int nj=0;nj<4;nj++)
        #pragma unroll
        for (int e=0;e<4;e++){
          const int m = bm + wr + mi*16 + 4*g + e;
          const int n = bn + wc + nj*16 + fr;
          const float vacc = acc[mi][nj][e];
          if constexpr (EPI==1){
            outb0[(size_t)m*N + n] = __float2bfloat16(vacc + bias[n] + resid[(size_t)m*N + n]);
          } else {
            float z = vacc + bias[n];
            outb0[(size_t)m*N + n] = __float2bfloat16(z > 0.f ? z : 0.f);
          }
        }
  }
}

// ====== gemm8n — FF2: 4-phase k-half-staggered schedule, BN=192 (R16-verified) =======
template<int NK>
__global__ __launch_bounds__(512, 2) void gemm8n(
    const bf16* __restrict__ A, const bf16* __restrict__ BT,
    const float* __restrict__ bias, const bf16* __restrict__ residb,
    float* __restrict__ outf)
{
  constexpr int K = NK*64;
  __shared__ char lds[114688];        // A: 2x32KB @0; B: 2x24KB @65536
  const int cpx = gridDim.x >> 3;
  const int wg  = (blockIdx.x & 7)*cpx + (blockIdx.x >> 3);
  const int bm = (wg >> 1)*256, bn = (wg & 1)*192;
  const int t = threadIdx.x, lane = t & 63, wid = t >> 6;
  const int wm = wid >> 2, wn = wid & 3;
  const int g = lane >> 4, fr = lane & 15;
  const size_t rowb = (size_t)K*2;
  const int sblkA = ((t&3) ^ ((t>>3)&3)) << 4;
  const int swzA  = (g ^ ((fr>>1)&3)) << 4;
  f32x4 acc[8][3] = {};

  const char* Ag = (const char*)A + (size_t)(bm + (t>>2))*rowb + sblkA;
  const size_t rstep = rowb*128;

  auto stgA = [&](int KH, int sl, int kt2){
    const char* src = Ag + (size_t)kt2*128 + KH*64;
    char* dst = lds + sl*32768 + KH*16384 + wid*1024;
    gload16(src,         dst);
    gload16(src + rstep, dst + 8192);
  };
  auto stgB = [&](int sl, int kt2){
    #pragma unroll
    for (int j=0;j<3;j++){
      int slot = t + j*512;
      int row = slot>>3, blk = slot&7;
      gload16((const char*)BT + (size_t)(bn + row)*rowb + (size_t)kt2*128 + ((blk ^ (row&7))<<4),
              lds + 65536 + sl*24576 + j*8192 + wid*1024);
    }
  };
  auto rdA = [&](bf16x8* af, int sl, int MH, int KS){
    const char* p = lds + sl*32768 + KS*16384 + (wm*128 + MH*64 + fr)*64 + swzA;
    #pragma unroll
    for (int mi=0;mi<4;mi++) af[mi] = *(const bf16x8*)(p + mi*1024);
  };
  auto rdB = [&](bf16x8* bq, int sl, int ks){
    #pragma unroll
    for (int nj=0;nj<3;nj++){
      int row = wn*48 + nj*16 + fr;
      bq[nj] = *(const bf16x8*)(lds + 65536 + sl*24576 + row*128 + (((ks*4+g) ^ (row&7))<<4));
    }
  };

#define MFMA12(MH) \
  __builtin_amdgcn_s_setprio(1); \
  _Pragma("unroll") \
  for (int mi=0;mi<4;mi++){ \
    _Pragma("unroll") \
    for (int nj=0;nj<3;nj++) \
      acc[(MH)*4+mi][nj] = __builtin_amdgcn_mfma_f32_16x16x32_bf16(af[mi], bq[nj], acc[(MH)*4+mi][nj], 0, 0, 0); \
  } \
  __builtin_amdgcn_s_setprio(0);

  stgA(0,0,0); stgB(0,0); stgA(1,0,0);
  asm volatile("s_waitcnt vmcnt(2)" ::: "memory");
  __builtin_amdgcn_s_barrier();

  #pragma unroll 1
  for (int kt=0; kt<NK; ++kt){
    const int sl = kt&1, sn = sl^1;
    const bool pf = (kt+1 < NK);
    bf16x8 af[4], bq[3];
    rdA(af, sl, 0, 0); rdB(bq, sl, 0);
    if (pf) stgA(0,sn,kt+1);
    __builtin_amdgcn_s_barrier();
    asm volatile("s_waitcnt lgkmcnt(0)" ::: "memory");
    __builtin_amdgcn_sched_barrier(0);
    MFMA12(0)
    __builtin_amdgcn_s_barrier();
    rdA(af, sl, 1, 0);
    if (pf){ stgB(sn,kt+1);
             asm volatile("s_waitcnt vmcnt(5)" ::: "memory"); }
    else     asm volatile("s_waitcnt vmcnt(0)" ::: "memory");
    __builtin_amdgcn_s_barrier();
    asm volatile("s_waitcnt lgkmcnt(0)" ::: "memory");
    __builtin_amdgcn_sched_barrier(0);
    MFMA12(1)
    __builtin_amdgcn_s_barrier();
    rdA(af, sl, 0, 1); rdB(bq, sl, 1);
    if (pf) stgA(1,sn,kt+1);
    __builtin_amdgcn_s_barrier();
    asm volatile("s_waitcnt lgkmcnt(0)" ::: "memory");
    __builtin_amdgcn_sched_barrier(0);
    MFMA12(0)
    __builtin_amdgcn_s_barrier();
    rdA(af, sl, 1, 1);
    if (pf) asm volatile("s_waitcnt vmcnt(2)" ::: "memory");
    __builtin_amdgcn_s_barrier();
    asm volatile("s_waitcnt lgkmcnt(0)" ::: "memory");
    __builtin_amdgcn_sched_barrier(0);
    MFMA12(1)
    __builtin_amdgcn_s_barrier();
  }
#undef MFMA12

  #pragma unroll
  for (int mi=0;mi<8;mi++)
    #pragma unroll
    for (int nj=0;nj<3;nj++)
      #pragma unroll
      for (int e=0;e<4;e++){
        const int m = bm + wm*128 + mi*16 + 4*g + e;
        const int n = bn + wn*48 + nj*16 + fr;
        outf[(size_t)m*CEMB + n] = acc[mi][nj][e] + bias[n] +
            b2f(*(const unsigned short*)&residb[(size_t)m*CEMB + n]);
      }
}

// ---------------- Causal flash attention — BALANCED wave->row mapping ---------------
// One block per (b,h), 4 waves. Wave w owns rows [16w,16w+16) of EVERY q-subtile s
// (s=0..3, 64 rows each): for kv-tile j all 4 waves compute subtiles s=j..3 -> perfectly
// balanced (max-wave MFMA 288 -> 180; old per-wave-q-tile wasted 37.5% at barriers).
// Static softmax max (SMAX): P=exp(s-SMAX); l folded via ones-row (vt row 64).
// Mask only at s==j: nj*16+fr > w*16+4g+e. LDS 26KB -> 4 blocks/CU.
__global__ __launch_bounds__(256) void attn_kernel(
    const bf16* __restrict__ q, const bf16* __restrict__ k,
    const bf16* __restrict__ v, bf16* __restrict__ out)
{
  __shared__ char kt_lds[64*128];     // K tile [s][d] single-XOR swizzled
  __shared__ char vt_lds[80*128];     // V^T [d][s] double-XOR swizzled; rows 64..79 const
  __shared__ char p_lds[4][16*128];   // per-wave 16-row P buffer, swizzled
  const int bh = blockIdx.x;
  const int bidx = bh / NHEAD, hidx = bh - bidx*NHEAD;
  const int t = threadIdx.x, lane = t & 63, w = t >> 6;
  const int g = lane >> 4, fr = lane & 15;
  const int lrow = lane >> 3;
  const int scol = ((lane & 7) ^ lrow) << 4;
  const size_t base = (size_t)bh * TSEQ * HSZ;

  // constant tail rows of vt: row 64 = ones (l-fold), 65..79 = zeros
  if (t < 128){
    unsigned int ones2 = 0x3F803F80u;
    uint4 vv;
    if ((t>>3) == 0) vv = uint4{ones2, ones2, ones2, ones2};
    else             vv = uint4{0u, 0u, 0u, 0u};
    *(uint4*)(vt_lds + (64 + (t>>3))*128 + (t&7)*16) = vv;
  }

  // q fragments: wave w's 16 rows of each subtile s: row = s*64 + w*16 + fr
  bf16x8 qf[4][2];
  #pragma unroll
  for (int s=0;s<4;s++)
    #pragma unroll
    for (int ks=0;ks<2;ks++)
      qf[s][ks] = *(const bf16x8*)(q + base + (size_t)(s*64 + w*16 + fr)*HSZ + ks*32 + g*8);

  f32x4 of[4][5] = {};   // of[s][nd]; nd=4: col 64 holds l

  #pragma unroll
  for (int j=0;j<4;j++){
    __syncthreads();
    // K tile via global_load_lds (pre-swizzled source)
    #pragma unroll
    for (int i=0;i<2;i++){
      int r0 = w*16 + i*8;
      gload16((const char*)(k + base + (size_t)(j*64 + r0 + lrow)*HSZ) + scol,
              kt_lds + r0*128);
    }
    // V tile: read (t,d) coalesced, write transposed [d][s], double-XOR swizzle
    #pragma unroll
    for (int i=0;i<2;i++){
      int chunk = t + i*256, r = chunk>>3, c = chunk&7;
      uint4 vv = *(const uint4*)(v + base + (size_t)(j*64 + r)*HSZ + c*8);
      const unsigned short* pv = (const unsigned short*)&vv;
      #pragma unroll
      for (int u=0;u<8;u++)
        *(unsigned short*)(vt_lds + (c*8+u)*128 + ((((r>>3) ^ u ^ c)&7)<<4) + (r&7)*2) = pv[u];
    }
    __syncthreads();
    #pragma unroll
    for (int s=0;s<4;s++){
      if (s < j) continue;               // compile-time pruned (j,s both unrolled)
      f32x4 sa[4] = {};
      #pragma unroll
      for (int ks=0;ks<2;ks++){
        bf16x8 kf[4];
        #pragma unroll
        for (int nj=0;nj<4;nj++)
          kf[nj] = *(const bf16x8*)(kt_lds + (nj*16+fr)*128 + (((ks*4+g)*16) ^ ((fr&7)<<4)));
        __builtin_amdgcn_s_setprio(1);
        #pragma unroll
        for (int nj=0;nj<4;nj++)
          sa[nj] = __builtin_amdgcn_mfma_f32_16x16x32_bf16(qf[s][ks], kf[nj], sa[nj], 0, 0, 0);
        __builtin_amdgcn_s_setprio(0);
      }
      if (s == j){                       // diagonal tile: causal mask
        #pragma unroll
        for (int nj=0;nj<4;nj++)
          #pragma unroll
          for (int e=0;e<4;e++)
            if (nj*16 + fr > w*16 + 4*g + e) sa[nj][e] = -1e30f;
      }
      // P = exp(s - SMAX) -> per-wave 16-row LDS buffer
      char* pl = p_lds[w];
      #pragma unroll
      for (int nj=0;nj<4;nj++)
        #pragma unroll
        for (int e=0;e<4;e++){
          int row16 = 4*g + e, col = nj*16 + fr;
          float p = __expf(sa[nj][e] - SMAX);
          *(bf16*)(pl + row16*128 + (((col>>3) ^ (row16&7))<<4) + (col&7)*2) =
              __float2bfloat16(p);
        }
      // PV: pa = P row fr; vf = V^T cols (+ ones-row for l)
      #pragma unroll
      for (int ks=0;ks<2;ks++){
        bf16x8 pa, vf[5];
        pa = *(const bf16x8*)(pl + fr*128 + (((ks*4+g)*16) ^ ((fr&7)<<4)));
        #pragma unroll
        for (int nd=0;nd<5;nd++){
          int d = nd*16 + fr;
          vf[nd] = *(const bf16x8*)(vt_lds + d*128 +
                   ((((ks*4+g) ^ (d&7) ^ ((d>>3)&7))&7)<<4));
        }
        __builtin_amdgcn_s_setprio(1);
        #pragma unroll
        for (int nd=0;nd<5;nd++)
          of[s][nd] = __builtin_amdgcn_mfma_f32_16x16x32_bf16(pa, vf[nd], of[s][nd], 0, 0, 0);
        __builtin_amdgcn_s_setprio(0);
      }
    }
  }
  // epilogue: l for row (4g+e) sits in of[s][4][e] of the fr==0 lane of this g-group
  #pragma unroll
  for (int s=0;s<4;s++){
    float rl[4];
    #pragma unroll
    for (int e=0;e<4;e++){
      float l = __shfl(of[s][4][e], (int)(lane & 48), 64);
      rl[e] = 1.0f / l;
    }
    #pragma unroll
    for (int nd=0;nd<4;nd++)
      #pragma unroll
      for (int e=0;e<4;e++){
        int row = s*64 + w*16 + 4*g + e;
        int d = nd*16 + fr;
        out[(size_t)(bidx*TSEQ + row)*CEMB + hidx*HSZ + d] =
            __float2bfloat16(of[s][nd][e] * rl[e]);
      }
  }
}

// ---------------- launch ----------------
extern "C" void kernel_launch(void* const* d_in, const int* in_sizes, int n_in,
                              void* d_out, int out_size, void* d_ws, size_t ws_size,
                              hipStream_t stream)
{
  const float* x     = (const float*)d_in[0];
  const float* Wq    = (const float*)d_in[1];
  const float* Wk    = (const float*)d_in[2];
  const float* Wv    = (const float*)d_in[3];
  const float* Wproj = (const float*)d_in[4];
  const float* bproj = (const float*)d_in[5];
  const float* W1    = (const float*)d_in[6];
  const float* b1    = (const float*)d_in[7];
  const float* W2    = (const float*)d_in[8];
  const float* b2    = (const float*)d_in[9];
  const float* ln1g  = (const float*)d_in[10];
  const float* ln1b  = (const float*)d_in[11];
  const float* ln2g  = (const float*)d_in[12];
  const float* ln2b  = (const float*)d_in[13];

  char* ws = (char*)d_ws;
  const size_t SA = (size_t)MROWS*CEMB*2;          // one bf16 M x C slot
  bf16* xn1    = (bf16*)(ws + 0*SA);               // LN1 out      (slot 0)
  bf16* qb     = (bf16*)(ws + 1*SA);               // q (b,h,t,d), pre-scaled
  bf16* kbuf   = (bf16*)(ws + 2*SA);               // k (b,h,t,d)
  bf16* vb     = (bf16*)(ws + 3*SA);               // v (b,h,t,d)
  bf16* attn_o = (bf16*)(ws + 0*SA);               // reuse slot 0 (xn1 dead after QKV)
  bf16* act    = (bf16*)(ws + 0*SA);               // FF1 out, slots 0-3
  bf16* hb     = (bf16*)(ws + 4*SA);               // LN2 out
  bf16* x1b    = (bf16*)(ws + 5*SA);               // residual stream after attn (bf16)
  char* wb     = ws + 5*SA + (size_t)MROWS*CEMB*4;
  bf16* qkvT   = (bf16*)wb;                                   // (1152, 384)
  bf16* projT  = (bf16*)(wb + (size_t)1152*384*2);            // (384, 384)
  bf16* w1T    = (bf16*)(wb + (size_t)(1152+384)*384*2);      // (1536, 384)
  bf16* w2T    = (bf16*)(wb + (size_t)(1152+384+1536)*384*2); // (384, 1536)

  dim3 blk(256), blk5(512);
  transpose_qkv<<<dim3(2,12,18), blk, 0, stream>>>(Wq, Wk, Wv, qkvT);
  transpose_to_bf16<<<dim3(12,12,1), blk, 0, stream>>>(Wproj, projT, CEMB, CEMB);
  transpose_to_bf16<<<dim3(48,12,1), blk, 0, stream>>>(W1,    w1T,   CEMB, FDIM);
  transpose_to_bf16<<<dim3(12,48,1), blk, 0, stream>>>(W2,    w2T,   FDIM, CEMB);

  ln_kernel<<<dim3(MROWS/4), blk, 0, stream>>>(x, ln1g, ln1b, xn1);
  gemm5<0,9,12><<<dim3(1152), blk5, 0, stream>>>(xn1, qkvT, nullptr, nullptr,
                                                 nullptr, qb, kbuf, vb);
  attn_kernel<<<dim3(768), blk, 0, stream>>>(qb, kbuf, vb, attn_o);
  gemm5<1,3,12><<<dim3(384), blk5, 0, stream>>>(attn_o, projT, bproj, x,
                                                nullptr, x1b, nullptr, nullptr);
  ln_kernel_b<<<dim3(MROWS/4), blk, 0, stream>>>(x1b, ln2g, ln2b, hb);
  gemm5<2,12,12><<<dim3(1536), blk5, 0, stream>>>(hb, w1T, b1, nullptr,
                                                  nullptr, act, nullptr, nullptr);
  gemm8n<24><<<dim3(256), blk5, 0, stream>>>(act, w2T, b2, x1b, (float*)d_out);
}